// Round 2
// baseline (4586.618 us; speedup 1.0000x reference)
//
#include <hip/hip_runtime.h>
#include <math.h>

#define BSZ 2048
#define DIM 2048
#define MS 6
#define NIT 29          // k = 1..29
#define LAMREG 1e-4f
#define XROWS (MS*DIM)  // 12288: row stride of the (bsz, 6, d) layouts
#define N2 ((size_t)BSZ*DIM)

typedef __bf16 bf16x8 __attribute__((ext_vector_type(8)));
typedef __bf16 bf16x4 __attribute__((ext_vector_type(4)));
typedef float  f32x4  __attribute__((ext_vector_type(4)));

__device__ __forceinline__ void async16(const void* g, void* l) {
    __builtin_amdgcn_global_load_lds((const __attribute__((address_space(1))) void*)g,
                                     (__attribute__((address_space(3))) void*)l, 16, 0, 0);
}

// swizzled LDS element offset for 16B chunk q (0..3) of row r in a [rows][32] bf16 panel
__device__ __forceinline__ int swz(int r, int q) {
    return r * 32 + ((q ^ ((r >> 1) & 3)) << 3);
}

// ---------------------------------------------------------------------------
// init: X[:,0] = x0, split-bf16 copy of x0, zero norm buckets
// ---------------------------------------------------------------------------
__global__ __launch_bounds__(256) void init_kernel(const float* __restrict__ x0,
                                                   float* __restrict__ Xout,
                                                   __bf16* __restrict__ Ahi,
                                                   __bf16* __restrict__ Alo,
                                                   float* __restrict__ norms) {
    int idx = blockIdx.x * 256 + threadIdx.x;
    if (idx < 16 * NIT) norms[idx] = 0.0f;     // 8 buckets x {g2,f2} per iter
    for (int i = idx; i < BSZ * DIM; i += gridDim.x * 256) {
        int b = i >> 11;
        int j = i & (DIM - 1);
        float v = x0[i];
        Xout[(size_t)b * XROWS + j] = v;
        __bf16 h = (__bf16)v;
        Ahi[i] = h;
        Alo[i] = (__bf16)(v - (float)h);
    }
}

// ---------------------------------------------------------------------------
// W (K x N, f32) -> W^T split into bf16 hi/lo:  WT[n][k] = W[k][n]
// ---------------------------------------------------------------------------
__global__ __launch_bounds__(256) void wt_split_kernel(const float* __restrict__ W,
                                                       __bf16* __restrict__ WThi,
                                                       __bf16* __restrict__ WTlo) {
    __shared__ float tile[32][33];
    const int tx = threadIdx.x & 31;
    const int ty = threadIdx.x >> 5;
    const int n0 = blockIdx.x * 32;
    const int k0 = blockIdx.y * 32;
#pragma unroll
    for (int i = 0; i < 32; i += 8)
        tile[ty + i][tx] = W[(size_t)(k0 + ty + i) * DIM + n0 + tx];
    __syncthreads();
#pragma unroll
    for (int i = 0; i < 32; i += 8) {
        float v = tile[tx][ty + i];
        __bf16 h = (__bf16)v;
        size_t o = (size_t)(n0 + ty + i) * DIM + k0 + tx;
        WThi[o] = h;
        WTlo[o] = (__bf16)(v - (float)h);
    }
}

// ---------------------------------------------------------------------------
// split-bf16 MFMA GEMM, split-K=2: 128x128 tiles, each block does K=1024.
// R2 theory: R1 (128x64, grid 512) staged 805 MB of L2/L3 traffic at the
// ~7.7 TB/s cache wall; 128x128 stages 537 MB and split-K keeps 2 blocks/CU
// for drain overlap. Wave tile 64x64: 341 B LDS-read per MFMA (was 512).
// Writes f32 partials to P[ks]; epilogue moved to mega_kernel.
// ---------------------------------------------------------------------------
__global__ __launch_bounds__(256, 2) void gemm_mfma_kernel(
    const __bf16* __restrict__ Ahi, const __bf16* __restrict__ Alo,
    const __bf16* __restrict__ WThi, const __bf16* __restrict__ WTlo,
    float* __restrict__ P)
{
    __shared__ __align__(16) __bf16 Ah[2][128 * 32];
    __shared__ __align__(16) __bf16 Al[2][128 * 32];
    __shared__ __align__(16) __bf16 Bh[2][128 * 32];
    __shared__ __align__(16) __bf16 Bl[2][128 * 32];   // 64 KB -> 2 blocks/CU

    // id bits: xcd = id&7 (dispatch round-robin), slot 5b, ks 1b.
    // Per XCD per ks: 4 A-panels (2 MB) + 8 B-panels (4 MB) -> lockstep K
    // streaming keeps the active K-window L2-resident.
    const int id = blockIdx.x;
    const int xcd = id & 7;
    const int rest = id >> 3;
    const int ks = rest >> 5;                  // K-half: 0 or 1
    const int slot = rest & 31;
    const int by = ((xcd & 3) << 2) | (slot & 3);      // 0..15
    const int bx = ((xcd >> 2) << 3) | (slot >> 2);    // 0..15
    const int m0 = by * 128;
    const int n0 = bx * 128;
    const int kbase = ks << 10;

    const int tid = threadIdx.x;
    const int l = tid & 63;
    const int w = tid >> 6;
    const int wm = (w & 1) * 64;    // wave's 64-row quadrant
    const int wn = (w >> 1) * 64;   // wave's 64-col quadrant
    const int rl = l & 15;
    const int quad = l >> 4;

    // staging: lane l of wave w covers row w*16 + (l>>2) (+64 for group 1),
    // LDS chunk position (l&3); load the XOR-swizzled global chunk so that
    // LDS position (row, c) holds global chunk c ^ ((row>>1)&3).
    const int srow = w * 16 + (l >> 2);
    const int gchunk = (l & 3) ^ ((l >> 3) & 3);
    const int scol = gchunk << 3;
    const size_t aoff = (size_t)(m0 + srow) * DIM + kbase + scol;
    const size_t boff = (size_t)(n0 + srow) * DIM + kbase + scol;
    const int lo = w * 512;

    f32x4 acc[4][4];
#pragma unroll
    for (int t = 0; t < 4; t++)
#pragma unroll
        for (int u = 0; u < 4; u++) acc[t][u] = (f32x4){0.f, 0.f, 0.f, 0.f};

    auto stage = [&](int kb, int s) {
        async16(Ahi + aoff + kb, &Ah[s][lo]);
        async16(Ahi + aoff + (size_t)64 * DIM + kb, &Ah[s][lo + 2048]);
        async16(Alo + aoff + kb, &Al[s][lo]);
        async16(Alo + aoff + (size_t)64 * DIM + kb, &Al[s][lo + 2048]);
        async16(WThi + boff + kb, &Bh[s][lo]);
        async16(WThi + boff + (size_t)64 * DIM + kb, &Bh[s][lo + 2048]);
        async16(WTlo + boff + kb, &Bl[s][lo]);
        async16(WTlo + boff + (size_t)64 * DIM + kb, &Bl[s][lo + 2048]);
    };
    auto compute = [&](int s) {
        bf16x8 ah[4], al[4];
#pragma unroll
        for (int t = 0; t < 4; t++) {
            const int r = wm + t * 16 + rl;
            ah[t] = *(const bf16x8*)&Ah[s][swz(r, quad)];
            al[t] = *(const bf16x8*)&Al[s][swz(r, quad)];
        }
#pragma unroll
        for (int u = 0; u < 4; u++) {
            const int c = wn + u * 16 + rl;
            bf16x8 bh = *(const bf16x8*)&Bh[s][swz(c, quad)];
            bf16x8 bl = *(const bf16x8*)&Bl[s][swz(c, quad)];
#pragma unroll
            for (int t = 0; t < 4; t++) {
                acc[t][u] = __builtin_amdgcn_mfma_f32_16x16x32_bf16(ah[t], bh, acc[t][u], 0, 0, 0);
                acc[t][u] = __builtin_amdgcn_mfma_f32_16x16x32_bf16(al[t], bh, acc[t][u], 0, 0, 0);
                acc[t][u] = __builtin_amdgcn_mfma_f32_16x16x32_bf16(ah[t], bl, acc[t][u], 0, 0, 0);
            }
        }
    };

    stage(0, 0);
    for (int k0 = 0; k0 < 1024; k0 += 64) {
        __syncthreads();               // drains buf0 loads (issued one phase ago)
        stage(k0 + 32, 1);
        compute(0);
        __syncthreads();               // drains buf1 loads
        if (k0 + 64 < 1024) stage(k0 + 64, 0);
        compute(1);
    }

    // write f32 partial tile to P[ks]
    float* Pk = P + (size_t)ks * N2;
#pragma unroll
    for (int t = 0; t < 4; t++) {
#pragma unroll
        for (int r = 0; r < 4; r++) {
            const int row = m0 + wm + t * 16 + quad * 4 + r;
            float* pr = Pk + (size_t)row * DIM + n0 + wn;
#pragma unroll
            for (int u = 0; u < 4; u++) pr[u * 16 + rl] = acc[t][u][r];
        }
    }
}

// ---------------------------------------------------------------------------
// mega: per-batch-row fusion of
//   (1) epilogue: z = P0+P1+bias, f = tanh(z), g = f - X[:,up], write F/G,
//       accumulate ||g||^2, ||f||^2 into bucketed norm atomics
//   (2) incremental Gram row: dots[j] = g_up . g_j  (j < nact)
//   (3) GGt fold + bordered (nact+1) solve -> alpha (thread 0, in LDS)
//   (4) xnew = sum alpha_i F_i -> X[:,nxt] + bf16 split (+result)
// fnew/g stay in registers across phases (no global read-back hazard);
// alpha never leaves the block. Replaces dots_solve + xnew + gemm epilogue.
// ---------------------------------------------------------------------------
__global__ __launch_bounds__(256) void mega_kernel(
    const float* __restrict__ P, const float* __restrict__ bias,
    float* __restrict__ Fb, float* __restrict__ Xb, float* __restrict__ Gb,
    float* __restrict__ GGt,
    __bf16* __restrict__ Ahi, __bf16* __restrict__ Alo,
    float* __restrict__ resultOrNull, float* __restrict__ normAcc,
    int up, int nact, int nxt)
{
    const int b = blockIdx.x;
    const int tid = threadIdx.x;
    const size_t rb = (size_t)b * XROWS;
    const size_t prow = (size_t)b * DIM;

    const f32x4* P0 = (const f32x4*)(P + prow);
    const f32x4* P1 = (const f32x4*)(P + N2 + prow);
    const f32x4* Bi = (const f32x4*)bias;
    const f32x4* Xu = (const f32x4*)(Xb + rb + (size_t)up * DIM);
    f32x4* Fu = (f32x4*)(Fb + rb + (size_t)up * DIM);
    f32x4* Gu = Gb ? (f32x4*)(Gb + rb + (size_t)up * DIM) : nullptr;

    f32x4 fv[2], gv[2];
    float s1 = 0.f, s2 = 0.f;
#pragma unroll
    for (int i = 0; i < 2; i++) {
        const int p4 = tid + 256 * i;
        f32x4 z = P0[p4] + P1[p4] + Bi[p4];
        f32x4 t;
        t.x = tanhf(z.x); t.y = tanhf(z.y); t.z = tanhf(z.z); t.w = tanhf(z.w);
        f32x4 xv = Xu[p4];
        f32x4 g = t - xv;
        fv[i] = t; gv[i] = g;
        Fu[p4] = t;
        if (Gu) Gu[p4] = g;
        s1 += g.x * g.x + g.y * g.y + g.z * g.z + g.w * g.w;
        s2 += t.x * t.x + t.y * t.y + t.z * t.z + t.w * t.w;
    }

    float acc[8];
#pragma unroll
    for (int p = 0; p < MS; p++) acc[p] = 0.f;
    acc[6] = s1; acc[7] = s2;

    if (nact > 0) {
#pragma unroll
        for (int j = 0; j < MS; j++) {
            if (j < nact) {
                if (j == up) { acc[j] = s1; continue; }
                float a = 0.f;
                if (Gb) {
                    const f32x4* Gj = (const f32x4*)(Gb + rb + (size_t)j * DIM);
#pragma unroll
                    for (int i = 0; i < 2; i++) {
                        const int p4 = tid + 256 * i;
                        f32x4 gj = Gj[p4];
                        a += gv[i].x * gj.x + gv[i].y * gj.y + gv[i].z * gj.z + gv[i].w * gj.w;
                    }
                } else {
                    const f32x4* Fj = (const f32x4*)(Fb + rb + (size_t)j * DIM);
                    const f32x4* Xj = (const f32x4*)(Xb + rb + (size_t)j * DIM);
#pragma unroll
                    for (int i = 0; i < 2; i++) {
                        const int p4 = tid + 256 * i;
                        f32x4 gj = Fj[p4] - Xj[p4];
                        a += gv[i].x * gj.x + gv[i].y * gj.y + gv[i].z * gj.z + gv[i].w * gj.w;
                    }
                }
                acc[j] = a;
            }
        }
    }

    // block-reduce 8 values (6 dots + s1 + s2)
#pragma unroll
    for (int p = 0; p < 8; p++) {
        float v = acc[p];
#pragma unroll
        for (int off = 32; off > 0; off >>= 1) v += __shfl_down(v, off);
        acc[p] = v;
    }
    __shared__ float red[4][8];
    __shared__ float Hs[7][8];
    __shared__ float alf[7];
    const int lane = tid & 63, wave = tid >> 6;
    if (lane == 0) {
#pragma unroll
        for (int p = 0; p < 8; p++) red[wave][p] = acc[p];
    }
    __syncthreads();

    if (tid == 0) {
        float d[8];
#pragma unroll
        for (int p = 0; p < 8; p++)
            d[p] = red[0][p] + red[1][p] + red[2][p] + red[3][p];
        if (normAcc) {
            atomicAdd(&normAcc[b & 7], d[6]);          // ||g||^2 bucket
            atomicAdd(&normAcc[8 + (b & 7)], d[7]);    // ||f||^2 bucket
        }
        if (nact > 0) {
            float* gg = GGt + (size_t)b * 36;
            for (int j = 0; j < nact; j++) {
                gg[up * 6 + j] = d[j];
                gg[j * 6 + up] = d[j];
            }
            const int np = nact + 1;
            for (int i = 0; i < np; i++) {
                for (int j = 0; j < np; j++) {
                    float v;
                    if (i == 0 && j == 0) v = 0.0f;
                    else if (i == 0 || j == 0) v = 1.0f;
                    else {
                        v = gg[(i - 1) * 6 + (j - 1)];
                        if (i == j) v += LAMREG;
                    }
                    Hs[i][j] = v;
                }
                Hs[i][7] = (i == 0) ? 1.0f : 0.0f;
            }
            for (int c = 0; c < np; c++) {
                int piv = c;
                float mx = fabsf(Hs[c][c]);
                for (int r = c + 1; r < np; r++) {
                    float a = fabsf(Hs[r][c]);
                    if (a > mx) { mx = a; piv = r; }
                }
                if (piv != c) {
                    for (int cc = c; cc <= 7; cc++) {
                        float t = Hs[c][cc]; Hs[c][cc] = Hs[piv][cc]; Hs[piv][cc] = t;
                    }
                }
                float inv = 1.0f / Hs[c][c];
                for (int r = c + 1; r < np; r++) {
                    float f = Hs[r][c] * inv;
                    for (int cc = c; cc <= 7; cc++) Hs[r][cc] -= f * Hs[c][cc];
                }
            }
            float sol[7];
            for (int c = np - 1; c >= 0; c--) {
                float s = Hs[c][7];
                for (int cc = c + 1; cc < np; cc++) s -= Hs[c][cc] * sol[cc];
                sol[c] = s / Hs[c][c];
            }
            for (int i = 0; i < nact; i++) alf[i] = sol[i + 1];
        }
    }
    __syncthreads();

    if (nxt >= 0) {
        f32x4 s[2] = {(f32x4){0.f,0.f,0.f,0.f}, (f32x4){0.f,0.f,0.f,0.f}};
        for (int i2 = 0; i2 < nact; i2++) {
            const float a = alf[i2];
            if (i2 == up) {
#pragma unroll
                for (int i = 0; i < 2; i++) {
                    s[i].x = fmaf(a, fv[i].x, s[i].x);
                    s[i].y = fmaf(a, fv[i].y, s[i].y);
                    s[i].z = fmaf(a, fv[i].z, s[i].z);
                    s[i].w = fmaf(a, fv[i].w, s[i].w);
                }
            } else {
                const f32x4* Fi = (const f32x4*)(Fb + rb + (size_t)i2 * DIM);
#pragma unroll
                for (int i = 0; i < 2; i++) {
                    const int p4 = tid + 256 * i;
                    f32x4 fj = Fi[p4];
                    s[i].x = fmaf(a, fj.x, s[i].x);
                    s[i].y = fmaf(a, fj.y, s[i].y);
                    s[i].z = fmaf(a, fj.z, s[i].z);
                    s[i].w = fmaf(a, fj.w, s[i].w);
                }
            }
        }
        f32x4* Xn = (f32x4*)(Xb + rb + (size_t)nxt * DIM);
#pragma unroll
        for (int i = 0; i < 2; i++) {
            const int p4 = tid + 256 * i;
            Xn[p4] = s[i];
            if (resultOrNull) ((f32x4*)(resultOrNull + prow))[p4] = s[i];
            bf16x4 hh, ll;
#pragma unroll
            for (int c = 0; c < 4; c++) {
                float v = s[i][c];
                __bf16 h = (__bf16)v;
                hh[c] = h;
                ll[c] = (__bf16)(v - (float)h);
            }
            *(bf16x4*)&Ahi[prow + (size_t)p4 * 4] = hh;
            *(bf16x4*)&Alo[prow + (size_t)p4 * 4] = ll;
        }
    }
}

__global__ void finalize_kernel(const float* __restrict__ norms,
                                float* __restrict__ rel, float* __restrict__ absd)
{
    int t = threadIdx.x;
    if (t < NIT) {
        float a2 = 0.f, f2 = 0.f;
        for (int i = 0; i < 8; i++) {
            a2 += norms[t * 16 + i];
            f2 += norms[t * 16 + 8 + i];
        }
        float a = sqrtf(a2);
        absd[t] = a;
        rel[t] = a / (1e-5f + sqrtf(f2));
    }
}

extern "C" void kernel_launch(void* const* d_in, const int* in_sizes, int n_in,
                              void* d_out, int out_size, void* d_ws, size_t ws_size,
                              hipStream_t stream) {
    const float* x0   = (const float*)d_in[0];
    const float* W    = (const float*)d_in[1];
    const float* bias = (const float*)d_in[2];

    float* out    = (float*)d_out;
    float* result = out;
    float* Xout   = out + (size_t)BSZ * DIM;
    float* rel    = Xout + (size_t)BSZ * MS * DIM;
    float* absd   = rel + NIT;

    char* ws = (char*)d_ws;
    float* F     = (float*)ws;                                   // 100.66 MB
    float* norms = F + (size_t)BSZ * MS * DIM;                   // 2 KB (16*NIT used)
    float* GGt   = norms + 512;                                  // 288 KB
    float* P     = GGt + (size_t)BSZ * 36;                       // 33.55 MB (2 planes)
    char* p = (char*)(P + 2 * N2);
    size_t off = ((size_t)(p - ws) + 255) & ~(size_t)255;
    __bf16* Ahi  = (__bf16*)(ws + off);  off += (size_t)BSZ * DIM * 2;
    __bf16* Alo  = (__bf16*)(ws + off);  off += (size_t)BSZ * DIM * 2;
    __bf16* WThi = (__bf16*)(ws + off);  off += (size_t)DIM * DIM * 2;
    __bf16* WTlo = (__bf16*)(ws + off);  off += (size_t)DIM * DIM * 2;
    // G array (100.66 MB) only if scratch is big enough
    float* G = nullptr;
    if (ws_size >= off + (size_t)BSZ * MS * DIM * 4 + 256) {
        off = (off + 255) & ~(size_t)255;
        G = (float*)(ws + off);
    }

    wt_split_kernel<<<dim3(64, 64), 256, 0, stream>>>(W, WThi, WTlo);
    init_kernel<<<2048, 256, 0, stream>>>(x0, Xout, Ahi, Alo, norms);

    // mega_j consumes gemm_j's P (f(arg_j)) and produces xnew_{j+1}:
    //   j=0:   arg = x0            (norms not traced)
    //   j>=1:  arg = xnew_j        (norms -> iter j)
    for (int j = 0; j <= NIT; j++) {
        gemm_mfma_kernel<<<512, 256, 0, stream>>>(Ahi, Alo, WThi, WTlo, P);
        int up   = j % MS;
        int nact = (j < NIT) ? ((j + 1 < MS) ? (j + 1) : MS) : 0;
        int nxt  = (j < NIT) ? ((j + 1) % MS) : -1;
        mega_kernel<<<BSZ, 256, 0, stream>>>(P, bias, F, Xout, G, GGt, Ahi, Alo,
                                             (j == NIT - 1) ? result : nullptr,
                                             (j >= 1) ? (norms + 16 * (j - 1)) : nullptr,
                                             up, nact, nxt);
    }
    finalize_kernel<<<1, 64, 0, stream>>>(norms, rel, absd);
}

// Round 3
// 3678.922 us; speedup vs baseline: 1.2467x; 1.2467x over previous
//
#include <hip/hip_runtime.h>
#include <math.h>

#define BSZ 2048
#define DIM 2048
#define MS 6
#define NIT 29          // k = 1..29
#define LAMREG 1e-4f
#define XROWS (MS*DIM)  // 12288: row stride of the (bsz, 6, d) layouts
#define N2 ((size_t)BSZ*DIM)

typedef __bf16 bf16x8 __attribute__((ext_vector_type(8)));
typedef __bf16 bf16x4 __attribute__((ext_vector_type(4)));
typedef float  f32x4  __attribute__((ext_vector_type(4)));

__device__ __forceinline__ void async16(const void* g, void* l) {
    __builtin_amdgcn_global_load_lds((const __attribute__((address_space(1))) void*)g,
                                     (__attribute__((address_space(3))) void*)l, 16, 0, 0);
}

// swizzled LDS element offset for 16B chunk q (0..3) of row r in a [rows][32] bf16 panel
__device__ __forceinline__ int swz(int r, int q) {
    return r * 32 + ((q ^ ((r >> 1) & 3)) << 3);
}

__device__ __forceinline__ f32x4 fma4(float a, f32x4 x, f32x4 acc) {
    acc.x = fmaf(a, x.x, acc.x);
    acc.y = fmaf(a, x.y, acc.y);
    acc.z = fmaf(a, x.z, acc.z);
    acc.w = fmaf(a, x.w, acc.w);
    return acc;
}
__device__ __forceinline__ float dot8(f32x4 u0, f32x4 u1, f32x4 a, f32x4 b) {
    return u0.x*a.x + u0.y*a.y + u0.z*a.z + u0.w*a.w
         + u1.x*b.x + u1.y*b.y + u1.z*b.z + u1.w*b.w;
}

// ---------------------------------------------------------------------------
// init: X[:,0] = x0, split-bf16 copy of x0, zero norm buckets
// ---------------------------------------------------------------------------
__global__ __launch_bounds__(256) void init_kernel(const float* __restrict__ x0,
                                                   float* __restrict__ Xout,
                                                   __bf16* __restrict__ Ahi,
                                                   __bf16* __restrict__ Alo,
                                                   float* __restrict__ norms) {
    int idx = blockIdx.x * 256 + threadIdx.x;
    if (idx < 16 * NIT) norms[idx] = 0.0f;     // 8 buckets x {g2,f2} per iter
    for (int i = idx; i < BSZ * DIM; i += gridDim.x * 256) {
        int b = i >> 11;
        int j = i & (DIM - 1);
        float v = x0[i];
        Xout[(size_t)b * XROWS + j] = v;
        __bf16 h = (__bf16)v;
        Ahi[i] = h;
        Alo[i] = (__bf16)(v - (float)h);
    }
}

// ---------------------------------------------------------------------------
// W (K x N, f32) -> W^T split into bf16 hi/lo:  WT[n][k] = W[k][n]
// ---------------------------------------------------------------------------
__global__ __launch_bounds__(256) void wt_split_kernel(const float* __restrict__ W,
                                                       __bf16* __restrict__ WThi,
                                                       __bf16* __restrict__ WTlo) {
    __shared__ float tile[32][33];
    const int tx = threadIdx.x & 31;
    const int ty = threadIdx.x >> 5;
    const int n0 = blockIdx.x * 32;
    const int k0 = blockIdx.y * 32;
#pragma unroll
    for (int i = 0; i < 32; i += 8)
        tile[ty + i][tx] = W[(size_t)(k0 + ty + i) * DIM + n0 + tx];
    __syncthreads();
#pragma unroll
    for (int i = 0; i < 32; i += 8) {
        float v = tile[tx][ty + i];
        __bf16 h = (__bf16)v;
        size_t o = (size_t)(n0 + ty + i) * DIM + k0 + tx;
        WThi[o] = h;
        WTlo[o] = (__bf16)(v - (float)h);
    }
}

// ---------------------------------------------------------------------------
// split-bf16 MFMA GEMM, split-K=2: 128x128 tiles, each block does K=1024.
// (unchanged from R2 — measured ~38 us)
// ---------------------------------------------------------------------------
__global__ __launch_bounds__(256, 2) void gemm_mfma_kernel(
    const __bf16* __restrict__ Ahi, const __bf16* __restrict__ Alo,
    const __bf16* __restrict__ WThi, const __bf16* __restrict__ WTlo,
    float* __restrict__ P)
{
    __shared__ __align__(16) __bf16 Ah[2][128 * 32];
    __shared__ __align__(16) __bf16 Al[2][128 * 32];
    __shared__ __align__(16) __bf16 Bh[2][128 * 32];
    __shared__ __align__(16) __bf16 Bl[2][128 * 32];   // 64 KB -> 2 blocks/CU

    const int id = blockIdx.x;
    const int xcd = id & 7;
    const int rest = id >> 3;
    const int ks = rest >> 5;                  // K-half: 0 or 1
    const int slot = rest & 31;
    const int by = ((xcd & 3) << 2) | (slot & 3);      // 0..15
    const int bx = ((xcd >> 2) << 3) | (slot >> 2);    // 0..15
    const int m0 = by * 128;
    const int n0 = bx * 128;
    const int kbase = ks << 10;

    const int tid = threadIdx.x;
    const int l = tid & 63;
    const int w = tid >> 6;
    const int wm = (w & 1) * 64;    // wave's 64-row quadrant
    const int wn = (w >> 1) * 64;   // wave's 64-col quadrant
    const int rl = l & 15;
    const int quad = l >> 4;

    const int srow = w * 16 + (l >> 2);
    const int gchunk = (l & 3) ^ ((l >> 3) & 3);
    const int scol = gchunk << 3;
    const size_t aoff = (size_t)(m0 + srow) * DIM + kbase + scol;
    const size_t boff = (size_t)(n0 + srow) * DIM + kbase + scol;
    const int lo = w * 512;

    f32x4 acc[4][4];
#pragma unroll
    for (int t = 0; t < 4; t++)
#pragma unroll
        for (int u = 0; u < 4; u++) acc[t][u] = (f32x4){0.f, 0.f, 0.f, 0.f};

    auto stage = [&](int kb, int s) {
        async16(Ahi + aoff + kb, &Ah[s][lo]);
        async16(Ahi + aoff + (size_t)64 * DIM + kb, &Ah[s][lo + 2048]);
        async16(Alo + aoff + kb, &Al[s][lo]);
        async16(Alo + aoff + (size_t)64 * DIM + kb, &Al[s][lo + 2048]);
        async16(WThi + boff + kb, &Bh[s][lo]);
        async16(WThi + boff + (size_t)64 * DIM + kb, &Bh[s][lo + 2048]);
        async16(WTlo + boff + kb, &Bl[s][lo]);
        async16(WTlo + boff + (size_t)64 * DIM + kb, &Bl[s][lo + 2048]);
    };
    auto compute = [&](int s) {
        bf16x8 ah[4], al[4];
#pragma unroll
        for (int t = 0; t < 4; t++) {
            const int r = wm + t * 16 + rl;
            ah[t] = *(const bf16x8*)&Ah[s][swz(r, quad)];
            al[t] = *(const bf16x8*)&Al[s][swz(r, quad)];
        }
#pragma unroll
        for (int u = 0; u < 4; u++) {
            const int c = wn + u * 16 + rl;
            bf16x8 bh = *(const bf16x8*)&Bh[s][swz(c, quad)];
            bf16x8 bl = *(const bf16x8*)&Bl[s][swz(c, quad)];
#pragma unroll
            for (int t = 0; t < 4; t++) {
                acc[t][u] = __builtin_amdgcn_mfma_f32_16x16x32_bf16(ah[t], bh, acc[t][u], 0, 0, 0);
                acc[t][u] = __builtin_amdgcn_mfma_f32_16x16x32_bf16(al[t], bh, acc[t][u], 0, 0, 0);
                acc[t][u] = __builtin_amdgcn_mfma_f32_16x16x32_bf16(ah[t], bl, acc[t][u], 0, 0, 0);
            }
        }
    };

    stage(0, 0);
    for (int k0 = 0; k0 < 1024; k0 += 64) {
        __syncthreads();               // drains buf0 loads (issued one phase ago)
        stage(k0 + 32, 1);
        compute(0);
        __syncthreads();               // drains buf1 loads
        if (k0 + 64 < 1024) stage(k0 + 64, 0);
        compute(1);
    }

    // write f32 partial tile to P[ks]
    float* Pk = P + (size_t)ks * N2;
#pragma unroll
    for (int t = 0; t < 4; t++) {
#pragma unroll
        for (int r = 0; r < 4; r++) {
            const int row = m0 + wm + t * 16 + quad * 4 + r;
            float* pr = Pk + (size_t)row * DIM + n0 + wn;
#pragma unroll
            for (int u = 0; u < 4; u++) pr[u * 16 + rl] = acc[t][u][r];
        }
    }
}

// ---------------------------------------------------------------------------
// mega: per-batch-row fusion of epilogue + Gram row + solve + xnew.
// R3: (a) steady-state (nact==6) solve is lane-parallel in wave 0 via shfl
//     (replaces ~20k-cycle serial thread-0 LDS Gauss that parked all waves
//     at the barrier in lockstep across the grid); (b) dots/xnew phases
//     issue all 12 plane-loads up front (no per-j vmcnt drains).
// ---------------------------------------------------------------------------
__global__ __launch_bounds__(256) void mega_kernel(
    const float* __restrict__ P, const float* __restrict__ bias,
    float* __restrict__ Fb, float* __restrict__ Xb, float* __restrict__ Gb,
    float* __restrict__ GGt,
    __bf16* __restrict__ Ahi, __bf16* __restrict__ Alo,
    float* __restrict__ resultOrNull, float* __restrict__ normAcc,
    int up, int nact, int nxt)
{
    const int b = blockIdx.x;
    const int tid = threadIdx.x;
    const int lane = tid & 63, wave = tid >> 6;
    const size_t rb = (size_t)b * XROWS;
    const size_t prow = (size_t)b * DIM;

    const f32x4* P0 = (const f32x4*)(P + prow);
    const f32x4* P1 = (const f32x4*)(P + N2 + prow);
    const f32x4* Bi = (const f32x4*)bias;
    const f32x4* Xu = (const f32x4*)(Xb + rb + (size_t)up * DIM);
    f32x4* Fu = (f32x4*)(Fb + rb + (size_t)up * DIM);
    f32x4* Gu = Gb ? (f32x4*)(Gb + rb + (size_t)up * DIM) : nullptr;

    const int t0 = tid, t1 = tid + 256;

    // ---- phase 1: epilogue ----
    f32x4 fv[2], gv[2];
    float s1 = 0.f, s2 = 0.f;
#pragma unroll
    for (int i = 0; i < 2; i++) {
        const int p4 = tid + 256 * i;
        f32x4 z = P0[p4] + P1[p4] + Bi[p4];
        f32x4 t;
        t.x = tanhf(z.x); t.y = tanhf(z.y); t.z = tanhf(z.z); t.w = tanhf(z.w);
        f32x4 xv = Xu[p4];
        f32x4 g = t - xv;
        fv[i] = t; gv[i] = g;
        Fu[p4] = t;
        if (Gu) Gu[p4] = g;
        s1 += g.x * g.x + g.y * g.y + g.z * g.z + g.w * g.w;
        s2 += t.x * t.x + t.y * t.y + t.z * t.z + t.w * t.w;
    }

    // ---- phase 2: dots ----
    float acc[8];
#pragma unroll
    for (int p = 0; p < MS; p++) acc[p] = 0.f;
    acc[6] = s1; acc[7] = s2;

    const bool fast = (nact == 6) && (Gb != nullptr);
    if (fast) {
        const f32x4* Gp = (const f32x4*)(Gb + rb);
        f32x4 a0 = Gp[t0],        b0 = Gp[t1];
        f32x4 a1 = Gp[512 + t0],  b1 = Gp[512 + t1];
        f32x4 a2 = Gp[1024 + t0], b2 = Gp[1024 + t1];
        f32x4 a3 = Gp[1536 + t0], b3 = Gp[1536 + t1];
        f32x4 a4 = Gp[2048 + t0], b4 = Gp[2048 + t1];
        f32x4 a5 = Gp[2560 + t0], b5 = Gp[2560 + t1];
        // replace the up-plane from registers (no same-address RAW reliance)
        if (up == 0) { a0 = gv[0]; b0 = gv[1]; }
        if (up == 1) { a1 = gv[0]; b1 = gv[1]; }
        if (up == 2) { a2 = gv[0]; b2 = gv[1]; }
        if (up == 3) { a3 = gv[0]; b3 = gv[1]; }
        if (up == 4) { a4 = gv[0]; b4 = gv[1]; }
        if (up == 5) { a5 = gv[0]; b5 = gv[1]; }
        acc[0] = dot8(gv[0], gv[1], a0, b0);
        acc[1] = dot8(gv[0], gv[1], a1, b1);
        acc[2] = dot8(gv[0], gv[1], a2, b2);
        acc[3] = dot8(gv[0], gv[1], a3, b3);
        acc[4] = dot8(gv[0], gv[1], a4, b4);
        acc[5] = dot8(gv[0], gv[1], a5, b5);
    } else if (nact > 0) {
#pragma unroll
        for (int j = 0; j < MS; j++) {
            if (j < nact) {
                if (j == up) { acc[j] = s1; continue; }
                float a = 0.f;
                if (Gb) {
                    const f32x4* Gj = (const f32x4*)(Gb + rb + (size_t)j * DIM);
#pragma unroll
                    for (int i = 0; i < 2; i++) {
                        const int p4 = tid + 256 * i;
                        f32x4 gj = Gj[p4];
                        a += gv[i].x * gj.x + gv[i].y * gj.y + gv[i].z * gj.z + gv[i].w * gj.w;
                    }
                } else {
                    const f32x4* Fj = (const f32x4*)(Fb + rb + (size_t)j * DIM);
                    const f32x4* Xj = (const f32x4*)(Xb + rb + (size_t)j * DIM);
#pragma unroll
                    for (int i = 0; i < 2; i++) {
                        const int p4 = tid + 256 * i;
                        f32x4 gj = Fj[p4] - Xj[p4];
                        a += gv[i].x * gj.x + gv[i].y * gj.y + gv[i].z * gj.z + gv[i].w * gj.w;
                    }
                }
                acc[j] = a;
            }
        }
    }

    // block-reduce 8 values (6 dots + s1 + s2)
#pragma unroll
    for (int p = 0; p < 8; p++) {
        float v = acc[p];
#pragma unroll
        for (int off = 32; off > 0; off >>= 1) v += __shfl_down(v, off);
        acc[p] = v;
    }
    __shared__ float red[4][8];
    __shared__ float dsh[8];
    __shared__ float Hs[7][8];
    __shared__ float alf[8];
    if (lane == 0) {
#pragma unroll
        for (int p = 0; p < 8; p++) red[wave][p] = acc[p];
    }
    __syncthreads();

    // ---- phase 3: solve ----
    if (fast) {
        if (wave == 0) {
            // lane p<8 holds reduced value p
            float dd = (lane < 8) ? (red[0][lane & 7] + red[1][lane & 7] +
                                     red[2][lane & 7] + red[3][lane & 7]) : 0.f;
            if (normAcc) {
                if (lane == 6) atomicAdd(&normAcc[b & 7], dd);
                if (lane == 7) atomicAdd(&normAcc[8 + (b & 7)], dd);
            }
            if (lane < 8) dsh[lane] = dd;
            float* gg = GGt + (size_t)b * 36;
            if (lane < 6) {                 // persist new Gram row/col
                gg[up * 6 + lane] = dd;
                gg[lane * 6 + up] = dd;
            }
            // build bordered 7x7 system; lane i = row i, r[0..6]=H, r[7]=rhs
            float r[8];
            {
                const int i = lane;
                const int a = i - 1;
                float grow[6] = {0, 0, 0, 0, 0, 0};
                if (i >= 1 && i < 7) {
#pragma unroll
                    for (int c = 0; c < 6; c++) grow[c] = gg[a * 6 + c]; // old entries
                }
                r[0] = (i == 0) ? 0.0f : 1.0f;
#pragma unroll
                for (int j = 1; j < 7; j++) {
                    const int c = j - 1;
                    float v;
                    if (i == 0) v = 1.0f;
                    else {
                        v = (a == up) ? dsh[c] : ((c == up) ? dsh[a] : grow[c]);
                        if (i == j) v += LAMREG;
                    }
                    r[j] = v;
                }
                r[7] = (i == 0) ? 1.0f : 0.0f;
            }
            // Gaussian elimination with partial pivoting, lane-parallel
#pragma unroll
            for (int c = 0; c < 7; c++) {
                float key = (lane >= c && lane < 7) ? fabsf(r[c]) : -1.0f;
                int idx = lane;
#pragma unroll
                for (int off = 32; off > 0; off >>= 1) {
                    float ok = __shfl_xor(key, off);
                    int oi = __shfl_xor(idx, off);
                    if (ok > key || (ok == key && oi < idx)) { key = ok; idx = oi; }
                }
                const int piv = idx;
                const int src = (lane == c) ? piv : ((lane == piv) ? c : lane);
#pragma unroll
                for (int k = 0; k < 8; k++) r[k] = __shfl(r[k], src);
                float pr[8];
#pragma unroll
                for (int k = 0; k < 8; k++) pr[k] = __shfl(r[k], c);
                const float inv = 1.0f / pr[c];
                const float f = (lane > c && lane < 7) ? r[c] * inv : 0.0f;
#pragma unroll
                for (int k = 0; k < 8; k++) r[k] = fmaf(-f, pr[k], r[k]);
            }
            // back substitution (progressive broadcast)
            float sol[7];
#pragma unroll
            for (int c = 6; c >= 0; c--) {
                float s = r[7];
#pragma unroll
                for (int cc = 6; cc > 0; cc--) {
                    if (cc > c) s = fmaf(-r[cc], sol[cc], s);
                }
                s /= r[c];
                sol[c] = __shfl(s, c);
            }
            if (lane < 6) alf[lane] = sol[lane + 1];
        }
    } else if (tid == 0) {
        float d[8];
#pragma unroll
        for (int p = 0; p < 8; p++)
            d[p] = red[0][p] + red[1][p] + red[2][p] + red[3][p];
        if (normAcc) {
            atomicAdd(&normAcc[b & 7], d[6]);
            atomicAdd(&normAcc[8 + (b & 7)], d[7]);
        }
        if (nact > 0) {
            float* gg = GGt + (size_t)b * 36;
            for (int j = 0; j < nact; j++) {
                gg[up * 6 + j] = d[j];
                gg[j * 6 + up] = d[j];
            }
            const int np = nact + 1;
            for (int i = 0; i < np; i++) {
                for (int j = 0; j < np; j++) {
                    float v;
                    if (i == 0 && j == 0) v = 0.0f;
                    else if (i == 0 || j == 0) v = 1.0f;
                    else {
                        v = gg[(i - 1) * 6 + (j - 1)];
                        if (i == j) v += LAMREG;
                    }
                    Hs[i][j] = v;
                }
                Hs[i][7] = (i == 0) ? 1.0f : 0.0f;
            }
            for (int c = 0; c < np; c++) {
                int piv = c;
                float mx = fabsf(Hs[c][c]);
                for (int rr = c + 1; rr < np; rr++) {
                    float a = fabsf(Hs[rr][c]);
                    if (a > mx) { mx = a; piv = rr; }
                }
                if (piv != c) {
                    for (int cc = c; cc <= 7; cc++) {
                        float t = Hs[c][cc]; Hs[c][cc] = Hs[piv][cc]; Hs[piv][cc] = t;
                    }
                }
                float inv = 1.0f / Hs[c][c];
                for (int rr = c + 1; rr < np; rr++) {
                    float f = Hs[rr][c] * inv;
                    for (int cc = c; cc <= 7; cc++) Hs[rr][cc] -= f * Hs[c][cc];
                }
            }
            float sol[7];
            for (int c = np - 1; c >= 0; c--) {
                float s = Hs[c][7];
                for (int cc = c + 1; cc < np; cc++) s -= Hs[c][cc] * sol[cc];
                sol[c] = s / Hs[c][c];
            }
            for (int i = 0; i < nact; i++) alf[i] = sol[i + 1];
        }
    }
    __syncthreads();

    // ---- phase 4: xnew ----
    if (nxt >= 0) {
        f32x4 s[2] = {(f32x4){0.f,0.f,0.f,0.f}, (f32x4){0.f,0.f,0.f,0.f}};
        if (nact == 6) {
            const f32x4* Fp = (const f32x4*)(Fb + rb);
            f32x4 a0 = Fp[t0],        b0 = Fp[t1];
            f32x4 a1 = Fp[512 + t0],  b1 = Fp[512 + t1];
            f32x4 a2 = Fp[1024 + t0], b2 = Fp[1024 + t1];
            f32x4 a3 = Fp[1536 + t0], b3 = Fp[1536 + t1];
            f32x4 a4 = Fp[2048 + t0], b4 = Fp[2048 + t1];
            f32x4 a5 = Fp[2560 + t0], b5 = Fp[2560 + t1];
            if (up == 0) { a0 = fv[0]; b0 = fv[1]; }
            if (up == 1) { a1 = fv[0]; b1 = fv[1]; }
            if (up == 2) { a2 = fv[0]; b2 = fv[1]; }
            if (up == 3) { a3 = fv[0]; b3 = fv[1]; }
            if (up == 4) { a4 = fv[0]; b4 = fv[1]; }
            if (up == 5) { a5 = fv[0]; b5 = fv[1]; }
            const float c0 = alf[0], c1 = alf[1], c2 = alf[2];
            const float c3 = alf[3], c4 = alf[4], c5 = alf[5];
            s[0] = fma4(c0, a0, s[0]); s[1] = fma4(c0, b0, s[1]);
            s[0] = fma4(c1, a1, s[0]); s[1] = fma4(c1, b1, s[1]);
            s[0] = fma4(c2, a2, s[0]); s[1] = fma4(c2, b2, s[1]);
            s[0] = fma4(c3, a3, s[0]); s[1] = fma4(c3, b3, s[1]);
            s[0] = fma4(c4, a4, s[0]); s[1] = fma4(c4, b4, s[1]);
            s[0] = fma4(c5, a5, s[0]); s[1] = fma4(c5, b5, s[1]);
        } else {
            for (int i2 = 0; i2 < nact; i2++) {
                const float a = alf[i2];
                if (i2 == up) {
#pragma unroll
                    for (int i = 0; i < 2; i++) s[i] = fma4(a, fv[i], s[i]);
                } else {
                    const f32x4* Fi = (const f32x4*)(Fb + rb + (size_t)i2 * DIM);
#pragma unroll
                    for (int i = 0; i < 2; i++) s[i] = fma4(a, Fi[tid + 256 * i], s[i]);
                }
            }
        }
        f32x4* Xn = (f32x4*)(Xb + rb + (size_t)nxt * DIM);
#pragma unroll
        for (int i = 0; i < 2; i++) {
            const int p4 = tid + 256 * i;
            Xn[p4] = s[i];
            if (resultOrNull) ((f32x4*)(resultOrNull + prow))[p4] = s[i];
            bf16x4 hh, ll;
#pragma unroll
            for (int c = 0; c < 4; c++) {
                float v = s[i][c];
                __bf16 h = (__bf16)v;
                hh[c] = h;
                ll[c] = (__bf16)(v - (float)h);
            }
            *(bf16x4*)&Ahi[prow + (size_t)p4 * 4] = hh;
            *(bf16x4*)&Alo[prow + (size_t)p4 * 4] = ll;
        }
    }
}

__global__ void finalize_kernel(const float* __restrict__ norms,
                                float* __restrict__ rel, float* __restrict__ absd)
{
    int t = threadIdx.x;
    if (t < NIT) {
        float a2 = 0.f, f2 = 0.f;
        for (int i = 0; i < 8; i++) {
            a2 += norms[t * 16 + i];
            f2 += norms[t * 16 + 8 + i];
        }
        float a = sqrtf(a2);
        absd[t] = a;
        rel[t] = a / (1e-5f + sqrtf(f2));
    }
}

extern "C" void kernel_launch(void* const* d_in, const int* in_sizes, int n_in,
                              void* d_out, int out_size, void* d_ws, size_t ws_size,
                              hipStream_t stream) {
    const float* x0   = (const float*)d_in[0];
    const float* W    = (const float*)d_in[1];
    const float* bias = (const float*)d_in[2];

    float* out    = (float*)d_out;
    float* result = out;
    float* Xout   = out + (size_t)BSZ * DIM;
    float* rel    = Xout + (size_t)BSZ * MS * DIM;
    float* absd   = rel + NIT;

    char* ws = (char*)d_ws;
    float* F     = (float*)ws;                                   // 100.66 MB
    float* norms = F + (size_t)BSZ * MS * DIM;                   // 2 KB (16*NIT used)
    float* GGt   = norms + 512;                                  // 288 KB
    float* P     = GGt + (size_t)BSZ * 36;                       // 33.55 MB (2 planes)
    char* p = (char*)(P + 2 * N2);
    size_t off = ((size_t)(p - ws) + 255) & ~(size_t)255;
    __bf16* Ahi  = (__bf16*)(ws + off);  off += (size_t)BSZ * DIM * 2;
    __bf16* Alo  = (__bf16*)(ws + off);  off += (size_t)BSZ * DIM * 2;
    __bf16* WThi = (__bf16*)(ws + off);  off += (size_t)DIM * DIM * 2;
    __bf16* WTlo = (__bf16*)(ws + off);  off += (size_t)DIM * DIM * 2;
    // G array (100.66 MB) only if scratch is big enough
    float* G = nullptr;
    if (ws_size >= off + (size_t)BSZ * MS * DIM * 4 + 256) {
        off = (off + 255) & ~(size_t)255;
        G = (float*)(ws + off);
    }

    wt_split_kernel<<<dim3(64, 64), 256, 0, stream>>>(W, WThi, WTlo);
    init_kernel<<<2048, 256, 0, stream>>>(x0, Xout, Ahi, Alo, norms);

    // mega_j consumes gemm_j's P (f(arg_j)) and produces xnew_{j+1}:
    //   j=0:   arg = x0            (norms not traced)
    //   j>=1:  arg = xnew_j        (norms -> iter j)
    for (int j = 0; j <= NIT; j++) {
        gemm_mfma_kernel<<<512, 256, 0, stream>>>(Ahi, Alo, WThi, WTlo, P);
        int up   = j % MS;
        int nact = (j < NIT) ? ((j + 1 < MS) ? (j + 1) : MS) : 0;
        int nxt  = (j < NIT) ? ((j + 1) % MS) : -1;
        mega_kernel<<<BSZ, 256, 0, stream>>>(P, bias, F, Xout, G, GGt, Ahi, Alo,
                                             (j == NIT - 1) ? result : nullptr,
                                             (j >= 1) ? (norms + 16 * (j - 1)) : nullptr,
                                             up, nact, nxt);
    }
    finalize_kernel<<<1, 64, 0, stream>>>(norms, rel, absd);
}